// Round 10
// baseline (490.248 us; speedup 1.0000x reference)
//
#include <hip/hip_runtime.h>
#include <math.h>

#define H 512
typedef unsigned short u16;
typedef __attribute__((ext_vector_type(8))) short bf16x8;
typedef __attribute__((ext_vector_type(4))) float f32x4;
typedef __attribute__((ext_vector_type(8))) unsigned short u16x8;

constexpr int LEAF0  = 21845;   // starts[8]
constexpr int NLEAF  = 65536;
constexpr int NNODES = 87381;

__device__ __forceinline__ u16 f2b(float f) {
    union { float f; unsigned u; } v; v.f = f;
    unsigned r = v.u + 0x7fffu + ((v.u >> 16) & 1u);  // RNE
    return (u16)(r >> 16);
}
__device__ __forceinline__ float b2f(u16 b) {
    union { unsigned u; float f; } v; v.u = ((unsigned)b) << 16; return v.f;
}
__device__ __forceinline__ float sigm(float x) {
    return __fdividef(1.f, 1.f + __expf(-x));
}
__device__ __forceinline__ float ftanh(float x) {
    float e = __expf(-2.f * fabsf(x));
    float r = __fdividef(1.f - e, 1.f + e);
    return copysignf(r, x);
}

template<int N> __device__ __forceinline__ void vmwait() {
    if constexpr (N == 0)        asm volatile("s_waitcnt vmcnt(0)" ::: "memory");
    else if constexpr (N == 2)   asm volatile("s_waitcnt vmcnt(2)" ::: "memory");
    else if constexpr (N == 3)   asm volatile("s_waitcnt vmcnt(3)" ::: "memory");
    else if constexpr (N == 4)   asm volatile("s_waitcnt vmcnt(4)" ::: "memory");
    else if constexpr (N == 6)   asm volatile("s_waitcnt vmcnt(6)" ::: "memory");
    else if constexpr (N == 8)   asm volatile("s_waitcnt vmcnt(8)" ::: "memory");
    else if constexpr (N == 9)   asm volatile("s_waitcnt vmcnt(9)" ::: "memory");
    else if constexpr (N == 12)  asm volatile("s_waitcnt vmcnt(12)" ::: "memory");
    else                         asm volatile("s_waitcnt vmcnt(16)" ::: "memory");
}

__device__ __forceinline__ void gload16(const u16* g, u16* l) {
    __builtin_amdgcn_global_load_lds(
        (const __attribute__((address_space(1))) void*)g,
        (__attribute__((address_space(3))) void*)l, 16, 0, 0);
}

// ---------------- vectorized fused epilogue (per-lane, NC contiguous cols) --
// EPI0 aux reads come from an LDS slice (child rows x WC cols, XOR-swizzled
// in 16B units). Bit-identical arithmetic to the scalar version.
template<int EPI, int NC, int WC>
__device__ __forceinline__ void epi_vec(
    const f32x4* va, int gr, int gc0,
    float* __restrict__ outf, u16* __restrict__ outb,
    u16* __restrict__ zrb, const u16* auxl, int lrow, int coffs, int outRow0)
{
    constexpr int NV = NC / 8;
    if constexpr (EPI == 1) {
        f32x4 ov[NC/4]; u16x8 hv[NV];
#pragma unroll
        for (int i = 0; i < NC; ++i) {
            float v = ftanh(va[i>>2][i&3]);
            ov[i>>2][i&3] = v; hv[i>>3][i&7] = f2b(v);
        }
        size_t o = (size_t)(outRow0 + gr) * H + gc0;
#pragma unroll
        for (int j = 0; j < NC/4; ++j) *(f32x4*)&outf[o + 4*j] = ov[j];
#pragma unroll
        for (int j = 0; j < NV; ++j) *(u16x8*)&outb[o + 8*j] = hv[j];
    } else if constexpr (EPI == 0) {
        auto aux_read = [&](int ch, int jj) -> u16x8 {
            int cr  = 4*lrow + ch;
            int key = (cr >> 2) & (WC/8 - 1);
            int j   = (coffs >> 3) + jj;
            return *(const u16x8*)&auxl[cr*WC + ((j ^ key) << 3)];
        };
        if (gc0 < H) {
            u16x8 zv[NV]; f32x4 hs[NC/4];
#pragma unroll
            for (int i = 0; i < NC; ++i) {
                zv[i>>3][i&7] = f2b(sigm(va[i>>2][i&3]));
                hs[i>>2][i&3] = 0.f;
            }
#pragma unroll
            for (int ch = 0; ch < 4; ++ch) {
#pragma unroll
                for (int j = 0; j < NV; ++j) {
                    u16x8 cv = aux_read(ch, j);
#pragma unroll
                    for (int k = 0; k < 8; ++k) {
                        int i = 8*j + k;
                        hs[i>>2][i&3] += b2f(cv[k]);
                    }
                }
            }
            u16x8 sv[NV];
#pragma unroll
            for (int i = 0; i < NC; ++i) sv[i>>3][i&7] = f2b(hs[i>>2][i&3]);
            size_t zo = (size_t)gr * 1024 + gc0;
#pragma unroll
            for (int j = 0; j < NV; ++j) *(u16x8*)&zrb[zo + 8*j] = zv[j];
#pragma unroll
            for (int j = 0; j < NV; ++j) *(u16x8*)&zrb[zo + H + 8*j] = sv[j];
        } else {
            f32x4 rr[NC/4];
#pragma unroll
            for (int i = 0; i < NC; ++i) rr[i>>2][i&3] = sigm(va[i>>2][i&3]);
            const int cc = gc0 - H;
#pragma unroll
            for (int ch = 0; ch < 4; ++ch) {
#pragma unroll
                for (int j = 0; j < NV; ++j) {
                    u16x8 cv = aux_read(ch, j);
                    u16x8 ov;
#pragma unroll
                    for (int k = 0; k < 8; ++k) {
                        int i = 8*j + k;
                        ov[k] = f2b(rr[i>>2][i&3] * b2f(cv[k]));
                    }
                    *(u16x8*)&outb[(size_t)gr*2048 + ch*H + cc + 8*j] = ov;
                }
            }
        }
    } else { // EPI == 2
        size_t zo = (size_t)gr * 1024 + gc0;
        u16x8 zv[NV], sv[NV];
#pragma unroll
        for (int j = 0; j < NV; ++j) zv[j] = *(const u16x8*)&zrb[zo + 8*j];
#pragma unroll
        for (int j = 0; j < NV; ++j) sv[j] = *(const u16x8*)&zrb[zo + H + 8*j];
        f32x4 ov[NC/4]; u16x8 hv[NV];
#pragma unroll
        for (int i = 0; i < NC; ++i) {
            float hc = ftanh(va[i>>2][i&3]);
            float z  = b2f(zv[i>>3][i&7]);
            float v  = b2f(sv[i>>3][i&7]) * z + (1.f - z) * hc;
            ov[i>>2][i&3] = v; hv[i>>3][i&7] = f2b(v);
        }
        size_t o = (size_t)(outRow0 + gr) * H + gc0;
#pragma unroll
        for (int j = 0; j < NC/4; ++j) *(f32x4*)&outf[o + 4*j] = ov[j];
#pragma unroll
        for (int j = 0; j < NV; ++j) *(u16x8*)&outb[o + 8*j] = hv[j];
    }
}

// ---- EPI0 aux slice staging: 64 child rows x WC cols into per-wave LDS ----
template<int WC>
__device__ __forceinline__ void stage_aux(
    u16* wls, const u16* auxg, int lane)
{
    constexpr int UPW = WC / 8;          // 16B units per row
    constexpr int NIT = 64 * UPW / 64;   // instructions per wave
#pragma unroll
    for (int it = 0; it < NIT; ++it) {
        int row = (it * 64 + lane) / UPW;
        int sp  = (lane & (UPW - 1)) ^ ((row >> 2) & (UPW - 1));
        gload16(auxg + row * H + sp * 8, &wls[it * 512]);
    }
}

// ---------------- fp32 -> bf16 conversion (all tensors, one launch) --------
__global__ void cvt_all(const float* __restrict__ s0, u16* __restrict__ d0, int n0,
                        const float* __restrict__ s1, u16* __restrict__ d1, int n1,
                        const float* __restrict__ s2, u16* __restrict__ d2, int n2,
                        const float* __restrict__ s3, u16* __restrict__ d3, int n3)
{
    int i = blockIdx.x * blockDim.x + threadIdx.x;
    int st = gridDim.x * blockDim.x;
    int tot = n0 + n1 + n2 + n3;
    for (; i < tot; i += st) {
        const float* s; u16* d; int k = i;
        if (k < n0)      { s = s0; d = d0; }
        else { k -= n0;
        if (k < n1)      { s = s1; d = d1; }
        else { k -= n1;
        if (k < n2)      { s = s2; d = d2; }
        else { k -= n2;    s = s3; d = d3; } } }
        float4 v = ((const float4*)s)[k];
        ushort4 o;
        o.x = f2b(v.x); o.y = f2b(v.y); o.z = f2b(v.z); o.w = f2b(v.w);
        ((ushort4*)d)[k] = o;
    }
}

// ====== 512-thread 256x128 deep-pipeline kernel (big levels) ================
// R6/R8 schedule topology (half-ring, counted vmcnt, ONE barrier/half,
// reg-dbuf frags, setprio, hoisted addressing) with ring DEEPENED:
// NBUF=6, prefetch depth 5 (was 4/3). Load slack = 4 half-periods ->
// period floor = HBM latency / 4 (was /2 — the measured ~1000cyc/half gap).
// Steady-state vmwait<9> (4 stages x3 outstanding, drain one); tail 6/3/0;
// prologue 5 stages + vmwait<12>. Ring safety: stage(h+5) overwrites slot
// (h-1)%6 whose readers' ds_reads were consumed by MFMA(h-1) before
// barrier h; vmwait-then-barrier still proves slot h+1 written before any
// wave's ld_frags(h+1). LDS = 6 x 24 KB = 144 KB <= 160 (1 block/CU, same).
template<int EPI>
__global__ __launch_bounds__(512, 2) void gemm8p(
    const u16* __restrict__ A, int lda, int M, int K,
    const u16* __restrict__ Bm,
    const float* __restrict__ bias,
    float* __restrict__ outf,
    u16*  __restrict__ outb,
    u16*  __restrict__ zrb,
    const u16* __restrict__ auxb,
    int outRow0)
{
    constexpr int MI = 4, NI = 4;
    constexpr int AH = 256 * 32;          // u16 per A half-slot (16 KB)
    constexpr int BH = 128 * 32;          // u16 per B half-slot (8 KB)

    __shared__ __align__(16) char smem[(6 * AH + 6 * BH) * 2];  // 144 KB
    u16* Asm = reinterpret_cast<u16*>(smem);
    u16* Bsm = reinterpret_cast<u16*>(smem) + 6 * AH;

    const int tid  = threadIdx.x;
    const int lane = tid & 63;
    const int wave = tid >> 6;
    const int wm = wave >> 1;             // 0..3 -> 64-row band of 256
    const int wn = wave & 1;              // 0..1 -> 64-col half of 128

    int bx, by;
    {
        const int gx = gridDim.x, gy = gridDim.y;
        int p = blockIdx.y * gx + blockIdx.x;
        if ((gy & 7) == 0) {
            int xcd = p & 7, slot = p >> 3;
            bx = slot % gx;
            by = (slot / gx) * 8 + xcd;
        } else { bx = blockIdx.x; by = blockIdx.y; }
    }
    const int row0 = by * 256;
    const int col0 = bx * 128;

    // ---- hoisted per-thread staging pointers (advance +32 per stage call) --
    const u16 *gA0, *gA1, *gB;
    int ldsA0, ldsA1, ldsB;
    {
        int e8 = tid, row = e8 >> 2, jc = e8 & 3, js = jc ^ ((row >> 1) & 3);
        gA0 = A + (size_t)(row0 + row) * lda + js * 8;  ldsA0 = e8 * 8;
        int e9 = 512 + tid, row2 = e9 >> 2, jc2 = e9 & 3,
            js2 = jc2 ^ ((row2 >> 1) & 3);
        gA1 = A + (size_t)(row0 + row2) * lda + js2 * 8; ldsA1 = e9 * 8;
        int br = tid >> 2, bjc = tid & 3, bjs = bjc ^ ((br >> 1) & 3);
        gB = Bm + (size_t)(col0 + br) * K + bjs * 8;     ldsB = tid * 8;
    }
    auto stage = [&](int slot) {
        gload16(gA0, &Asm[slot * AH + ldsA0]); gA0 += 32;
        gload16(gA1, &Asm[slot * AH + ldsA1]); gA1 += 32;
        gload16(gB,  &Bsm[slot * BH + ldsB]);  gB  += 32;
    };

    const int rl = lane & 15;
    const int qq = lane >> 4;
    const int ua   = qq ^ ((rl >> 1) & 3);
    const int aoff = (wm * 64 + rl) * 32 + ua * 8;
    const int boff = (wn * 64 + rl) * 32 + ua * 8;

    auto ld_frags = [&](int slot, bf16x8 (&fa)[MI], bf16x8 (&fb)[NI]) {
        const u16* aB = Asm + slot * AH + aoff;
        const u16* bB = Bsm + slot * BH + boff;
#pragma unroll
        for (int mi = 0; mi < MI; ++mi)
            fa[mi] = *(const bf16x8*)(aB + mi * 512);
#pragma unroll
        for (int ni = 0; ni < NI; ++ni)
            fb[ni] = *(const bf16x8*)(bB + ni * 512);
    };

    f32x4 acc[MI][NI] = {};
    const int nh = K / 32;                // 16 or 64
    bf16x8 fa0[MI], fb0[NI], fa1[MI], fb1[NI];

    stage(0); stage(1); stage(2); stage(3); stage(4);
    vmwait<12>();                         // drain slot 0 (5x3=15 -> 12)
    __builtin_amdgcn_s_barrier();
    asm volatile("" ::: "memory");
    ld_frags(0, fa0, fb0);

    auto iter = [&](int h, bf16x8 (&cfa)[MI], bf16x8 (&cfb)[NI],
                           bf16x8 (&nfa)[MI], bf16x8 (&nfb)[NI]) {
        const int rem = nh - h;
        if (rem >= 5)      vmwait<9>();   // drain h+1; leave h+2..h+4
        else if (rem == 4) vmwait<6>();
        else if (rem == 3) vmwait<3>();
        else               vmwait<0>();
        __builtin_amdgcn_s_barrier();
        asm volatile("" ::: "memory");
        if (h + 5 < nh) stage((h + 5) % 6);
        if (h + 1 < nh) ld_frags((h + 1) % 6, nfa, nfb);
        __builtin_amdgcn_s_setprio(1);
#pragma unroll
        for (int mi = 0; mi < MI; ++mi)
#pragma unroll
            for (int ni = 0; ni < NI; ++ni)
                acc[mi][ni] = __builtin_amdgcn_mfma_f32_16x16x32_bf16(
                    cfa[mi], cfb[ni], acc[mi][ni], 0, 0, 0);
        __builtin_amdgcn_s_setprio(0);
    };

    for (int h = 0; h < nh; h += 2) {
        iter(h,     fa0, fb0, fa1, fb1);
        iter(h + 1, fa1, fb1, fa0, fb0);
    }

    // ---- epilogue ----
    float bcol[NI];
#pragma unroll
    for (int ni = 0; ni < NI; ++ni)
        bcol[ni] = bias[col0 + wn * 64 + ni * 16 + rl];

    __syncthreads();
    char* wreg = smem + wave * 8192;
    float* Csw = reinterpret_cast<float*>(wreg);
    u16*   wls = reinterpret_cast<u16*>(wreg);
    const int rq  = lane >> 4;
    const int rl2 = lane & 15;
#pragma unroll
    for (int mi = 0; mi < MI; ++mi) {
#pragma unroll
        for (int ni = 0; ni < NI; ++ni)
#pragma unroll
            for (int q = 0; q < 4; ++q)
                Csw[(rq*4 + q)*68 + ni*16 + rl2] = acc[mi][ni][q] + bcol[ni];
        asm volatile("s_waitcnt lgkmcnt(0)" ::: "memory");
        f32x4 va[4];
#pragma unroll
        for (int j = 0; j < 4; ++j)
            va[j] = *(const f32x4*)&Csw[rl2*68 + rq*16 + 4*j];
        if constexpr (EPI == 0) {
            asm volatile("s_waitcnt lgkmcnt(0)" ::: "memory");
            int c0 = ((col0 < H) ? col0 : col0 - H) + wn * 64;
            const u16* auxg = auxb + (size_t)(4*(row0 + wm*64 + mi*16)) * H + c0;
            stage_aux<64>(wls, auxg, lane);
            vmwait<0>();
        }
        int gr  = row0 + wm*64 + mi*16 + rl2;
        int gc0 = col0 + wn*64 + rq*16;
        if (gr < M)
            epi_vec<EPI, 16, 64>(va, gr, gc0, outf, outb, zrb, wls, rl2, rq*16, outRow0);
    }
}

// ============ 512-thread 128x128 kernel (L6): 8 waves, BK=32 ================
template<int EPI>
__global__ __launch_bounds__(512) void gemm512(
    const u16* __restrict__ A, int lda, int M, int K,
    const u16* __restrict__ Bm,
    const float* __restrict__ bias,
    float* __restrict__ outf,
    u16*  __restrict__ outb,
    u16*  __restrict__ zrb,
    const u16* __restrict__ auxb,
    int outRow0)
{
    __shared__ __align__(16) char smem[4*128*32*2 * 2];  // 65536 B
    u16* Asm = reinterpret_cast<u16*>(smem);
    u16* Bsm = reinterpret_cast<u16*>(smem) + 4 * 128 * 32;

    const int tid  = threadIdx.x;
    const int lane = tid & 63;
    const int wave = tid >> 6;
    const int wm = wave >> 2;
    const int wn = wave & 3;

    int bx, by;
    {
        const int gx = gridDim.x, gy = gridDim.y;
        int p = blockIdx.y * gx + blockIdx.x;
        if ((gy & 7) == 0) {
            int xcd = p & 7, slot = p >> 3;
            bx = slot % gx;
            by = (slot / gx) * 8 + xcd;
        } else { bx = blockIdx.x; by = blockIdx.y; }
    }
    const int row0 = by * 128;
    const int col0 = bx * 128;

    const u16 *gA, *gB;
    int ldsE;
    {
        int row = tid >> 2, jc = tid & 3, js = jc ^ ((row >> 1) & 3);
        gA = A  + (size_t)(row0 + row) * lda + js * 8;
        gB = Bm + (size_t)(col0 + row) * K   + js * 8;
        ldsE = tid * 8;
    }
    auto stage = [&](int b) {
        gload16(gA, &Asm[b * (128*32) + ldsE]); gA += 32;
        gload16(gB, &Bsm[b * (128*32) + ldsE]); gB += 32;
    };

    const int rl = lane & 15;
    const int qq = lane >> 4;
    const int ua   = qq ^ ((rl >> 1) & 3);
    const int aoff = (wm * 64 + rl) * 32 + ua * 8;
    const int boff = (wn * 32 + rl) * 32 + ua * 8;

    f32x4 acc[4][2] = {};
    const int nt = K / 32;
    stage(0);
    stage(1);

    for (int t = 0; t < nt; ++t) {
        if (t + 2 < nt) {
            stage((t + 2) & 3);
            vmwait<4>();
        } else if (t + 2 == nt) {
            vmwait<2>();
        } else {
            vmwait<0>();
        }
        __builtin_amdgcn_s_barrier();
        asm volatile("" ::: "memory");

        const u16* aB = Asm + (t & 3) * (128*32) + aoff;
        const u16* bB = Bsm + (t & 3) * (128*32) + boff;
        bf16x8 af[4], bfr[2];
#pragma unroll
        for (int mi = 0; mi < 4; ++mi)
            af[mi] = *(const bf16x8*)(aB + mi * 512);
#pragma unroll
        for (int ni = 0; ni < 2; ++ni)
            bfr[ni] = *(const bf16x8*)(bB + ni * 512);
#pragma unroll
        for (int mi = 0; mi < 4; ++mi)
#pragma unroll
            for (int ni = 0; ni < 2; ++ni)
                acc[mi][ni] = __builtin_amdgcn_mfma_f32_16x16x32_bf16(
                    af[mi], bfr[ni], acc[mi][ni], 0, 0, 0);
    }

    // ---- epilogue ----
    float bcol[2];
#pragma unroll
    for (int ni = 0; ni < 2; ++ni)
        bcol[ni] = bias[col0 + wn * 32 + ni * 16 + rl];

    __syncthreads();
    char* wreg = smem + wave * 8192;
    float* Csw = reinterpret_cast<float*>(wreg);
    u16*   wls = reinterpret_cast<u16*>(wreg);
    const int rq  = lane >> 4;
    const int rl2 = lane & 15;
#pragma unroll
    for (int mi = 0; mi < 4; ++mi) {
#pragma unroll
        for (int ni = 0; ni < 2; ++ni)
#pragma unroll
            for (int q = 0; q < 4; ++q)
                Csw[(rq*4 + q)*36 + ni*16 + rl2] = acc[mi][ni][q] + bcol[ni];
        asm volatile("s_waitcnt lgkmcnt(0)" ::: "memory");
        f32x4 va[2];
#pragma unroll
        for (int j = 0; j < 2; ++j)
            va[j] = *(const f32x4*)&Csw[rl2*36 + rq*8 + 4*j];
        if constexpr (EPI == 0) {
            asm volatile("s_waitcnt lgkmcnt(0)" ::: "memory");
            int c0 = ((col0 < H) ? col0 : col0 - H) + wn * 32;
            const u16* auxg = auxb + (size_t)(4*(row0 + wm*64 + mi*16)) * H + c0;
            stage_aux<32>(wls, auxg, lane);
            vmwait<0>();
        }
        int gr  = row0 + wm*64 + mi*16 + rl2;
        int gc0 = col0 + wn*32 + rq*8;
        if (gr < M)
            epi_vec<EPI, 8, 32>(va, gr, gc0, outf, outb, zrb, wls, rl2, rq*8, outRow0);
    }
}

// ====== 256-thread 64x64 split-K kernel (small levels, m <= 1024) ===========
// 4 waves each own K/4; wave-PRIVATE LDS ring (NBUF=3, BK=32, depth-2
// prefetch, counted per-wave vmcnt 16/8/0, NO barriers in the K-loop).
// Then deterministic 4-partial LDS reduction (w0+w1+w2+w3) + fused epilogue.
template<int EPI>
__global__ __launch_bounds__(256, 1) void gemm_sk(
    const u16* __restrict__ A, int lda, int M, int K,
    const u16* __restrict__ Bm,
    const float* __restrict__ bias,
    float* __restrict__ outf,
    u16*  __restrict__ outb,
    u16*  __restrict__ zrb,
    const u16* __restrict__ auxb,
    int outRow0)
{
    __shared__ __align__(16) char smem[98304];   // 96 KB
    u16* ring = reinterpret_cast<u16*>(smem);    // 4 waves x 3 slots x 8 KB

    const int tid  = threadIdx.x;
    const int lane = tid & 63;
    const int wave = tid >> 6;                   // 0..3 -> K chunk
    const int row0 = blockIdx.y * 64;
    const int col0 = blockIdx.x * 64;
    const int KC   = K >> 2;                     // 512
    const int kb0  = wave * KC;
    const int NS   = KC / 32;                    // 16

    u16* wring = ring + wave * 12288;            // u16 units (24 KB)

    auto stage = [&](int sl, int kt) {
        u16* As = wring + sl * 4096;
        u16* Bs = As + 2048;
#pragma unroll
        for (int it = 0; it < 4; ++it) {
            int e8  = it * 64 + lane;
            int row = e8 >> 2;                   // 0..63
            int jc  = e8 & 3;
            int js  = jc ^ ((row >> 1) & 3);
            int ar = row0 + row; if (ar >= M) ar = M - 1;
            gload16(A + (size_t)ar * lda + kt + js * 8, &As[e8 * 8]);
            gload16(Bm + (size_t)(col0 + row) * K + kt + js * 8, &Bs[e8 * 8]);
        }
    };

    const int rl = lane & 15;
    const int qq = lane >> 4;
    const int ua   = qq ^ ((rl >> 1) & 3);
    const int aoff = rl * 32 + ua * 8;

    f32x4 acc[4][4] = {};
    stage(0, kb0);
    stage(1, kb0 + 32);

    for (int s = 0; s < NS; ++s) {
        if (s + 2 < NS) { stage((s + 2) % 3, kb0 + (s + 2) * 32); vmwait<16>(); }
        else if (s + 1 < NS) vmwait<8>();
        else                 vmwait<0>();
        asm volatile("" ::: "memory");
        const u16* As = wring + (s % 3) * 4096;
        const u16* Bs = As + 2048;
        bf16x8 af[4], bfr[4];
#pragma unroll
        for (int mi = 0; mi < 4; ++mi)
            af[mi] = *(const bf16x8*)&As[aoff + mi * 512];
#pragma unroll
        for (int ni = 0; ni < 4; ++ni)
            bfr[ni] = *(const bf16x8*)&Bs[aoff + ni * 512];
#pragma unroll
        for (int mi = 0; mi < 4; ++mi)
#pragma unroll
            for (int ni = 0; ni < 4; ++ni)
                acc[mi][ni] = __builtin_amdgcn_mfma_f32_16x16x32_bf16(
                    af[mi], bfr[ni], acc[mi][ni], 0, 0, 0);
    }

    // ---- partials to LDS (deterministic reduce order w0..w3) ----
    __syncthreads();                             // all waves done with rings
    float* P  = reinterpret_cast<float*>(smem);  // 4 x 4096 f32 = 64 KB
    float* Pw = P + wave * 4096;
    const int rq = lane >> 4;
#pragma unroll
    for (int mi = 0; mi < 4; ++mi)
#pragma unroll
        for (int ni = 0; ni < 4; ++ni)
#pragma unroll
            for (int q = 0; q < 4; ++q)
                Pw[(mi*16 + rq*4 + q) * 64 + ni*16 + rl] = acc[mi][ni][q];
    asm volatile("s_waitcnt lgkmcnt(0)" ::: "memory");
    __syncthreads();

    // ---- (EPI0) stage aux slice: 256 child rows x 64 cols, swizzled ----
    u16* auxl = reinterpret_cast<u16*>(smem + 65536);   // 32 KB
    if constexpr (EPI == 0) {
        int c0 = (col0 < H) ? col0 : col0 - H;
        const u16* auxg = auxb + (size_t)(4 * row0) * H + c0;
        const int maxr = 4 * (M - row0);                 // valid child rows
#pragma unroll
        for (int it = 0; it < 8; ++it) {
            int e   = it * 256 + tid;
            int row = e >> 3;                            // 0..255
            int crow = row; if (crow >= maxr) crow = maxr - 1;
            int sp  = (e & 7) ^ ((row >> 2) & 7);
            gload16(auxg + (size_t)crow * H + sp * 8, &auxl[e * 8]);
        }
    }

    // ---- reduce + bias + epilogue (thread -> 1 row x 16 cols) ----
    const int orow = tid >> 2;                   // 0..63
    const int cq   = tid & 3;
    f32x4 va[4];
#pragma unroll
    for (int j = 0; j < 4; ++j) {
        f32x4 v = *(const f32x4*)&P[orow*64 + cq*16 + 4*j];
#pragma unroll
        for (int w = 1; w < 4; ++w)
            v += *(const f32x4*)&P[w*4096 + orow*64 + cq*16 + 4*j];
        v += *(const f32x4*)&bias[col0 + cq*16 + 4*j];
        va[j] = v;
    }
    if constexpr (EPI == 0) vmwait<0>();
    asm volatile("s_waitcnt lgkmcnt(0)" ::: "memory");
    int gr = row0 + orow;
    if (gr < M)
        epi_vec<EPI, 16, 64>(va, gr, col0 + cq*16, outf, outb, zrb,
                             auxl, orow, cq*16, outRow0);
}

extern "C" void kernel_launch(void* const* d_in, const int* in_sizes, int n_in,
                              void* d_out, int out_size, void* d_ws, size_t ws_size,
                              hipStream_t stream) {
    const float* x     = (const float*)d_in[0];
    const float* Ww    = (const float*)d_in[1];
    const float* Wb    = (const float*)d_in[2];
    const float* Uzr_w = (const float*)d_in[3];
    const float* Uzr_b = (const float*)d_in[4];
    const float* Uh_w  = (const float*)d_in[5];
    const float* Uh_b  = (const float*)d_in[6];
    float* out = (float*)d_out;

    char* ws = (char*)d_ws;
    size_t off = 0;
    u16* hb   = (u16*)(ws + off); off += (size_t)NNODES * H * 2;       // 89.5 MB
    u16* zr   = (u16*)(ws + off); off += (size_t)16384 * 1024 * 2;     // 32 MB
    u16* rhxb = (u16*)(ws + off); off += (size_t)16384 * 2048 * 2;     // 64 MB
    u16* Wwb  = (u16*)(ws + off); off += (size_t)512 * 512 * 2;
    u16* Uzrb = (u16*)(ws + off); off += (size_t)1024 * 2048 * 2;
    u16* Uhb  = (u16*)(ws + off); off += (size_t)512 * 2048 * 2;

    // 1) convert weights + leaf x to bf16 (single launch)
    cvt_all<<<dim3(8192), 256, 0, stream>>>(
        Ww, Wwb, 512 * 512 / 4,
        Uzr_w, Uzrb, 1024 * 2048 / 4,
        Uh_w, Uhb, 512 * 2048 / 4,
        x + (size_t)LEAF0 * H, rhxb, NLEAF * H / 4);

    // 2) leaf GEMM: h = tanh(x @ Ww^T + Wb) — deep-pipeline 256x128
    gemm8p<1><<<dim3(H / 128, NLEAF / 256), 512, 0, stream>>>(
        rhxb, H, NLEAF, H, Wwb, Wb, out, hb, nullptr, nullptr, LEAF0);

    // 3) levels 7..0
    static const int pow4[9] = {1, 4, 16, 64, 256, 1024, 4096, 16384, 65536};
    int starts[10]; starts[0] = 0;
    for (int l = 0; l < 9; ++l) starts[l + 1] = starts[l] + pow4[l];

    for (int l = 7; l >= 0; --l) {
        int s = starts[l], m = pow4[l];
        int cs = 4 * s + 1;  // children rows are contiguous: [cs, cs+4m)
        if (m >= 16384) {
            gemm8p<0><<<dim3(1024 / 128, m / 256), 512, 0, stream>>>(
                hb + (size_t)cs * H, 2048, m, 2048, Uzrb, Uzr_b,
                nullptr, rhxb, zr, hb + (size_t)cs * H, 0);
            gemm8p<2><<<dim3(H / 128, m / 256), 512, 0, stream>>>(
                rhxb, 2048, m, 2048, Uhb, Uh_b,
                out, hb, zr, nullptr, s);
        } else if (m >= 4096) {
            int gm = (m + 127) / 128;
            gemm512<0><<<dim3(1024 / 128, gm), 512, 0, stream>>>(
                hb + (size_t)cs * H, 2048, m, 2048, Uzrb, Uzr_b,
                nullptr, rhxb, zr, hb + (size_t)cs * H, 0);
            gemm512<2><<<dim3(H / 128, gm), 512, 0, stream>>>(
                rhxb, 2048, m, 2048, Uhb, Uh_b,
                out, hb, zr, nullptr, s);
        } else {
            // small levels: 64x64 split-K kernel, grid fills the GPU better
            int gm = (m + 63) / 64;
            gemm_sk<0><<<dim3(1024 / 64, gm), 256, 0, stream>>>(
                hb + (size_t)cs * H, 2048, m, 2048, Uzrb, Uzr_b,
                nullptr, rhxb, zr, hb + (size_t)cs * H, 0);
            gemm_sk<2><<<dim3(512 / 64, gm), 256, 0, stream>>>(
                rhxb, 2048, m, 2048, Uhb, Uh_b,
                out, hb, zr, nullptr, s);
        }
    }
}

// Round 11
// 475.654 us; speedup vs baseline: 1.0307x; 1.0307x over previous
//
#include <hip/hip_runtime.h>
#include <math.h>

#define H 512
typedef unsigned short u16;
typedef __attribute__((ext_vector_type(8))) short bf16x8;
typedef __attribute__((ext_vector_type(4))) float f32x4;
typedef __attribute__((ext_vector_type(8))) unsigned short u16x8;

constexpr int LEAF0  = 21845;   // starts[8]
constexpr int NLEAF  = 65536;
constexpr int NNODES = 87381;

__device__ __forceinline__ u16 f2b(float f) {
    union { float f; unsigned u; } v; v.f = f;
    unsigned r = v.u + 0x7fffu + ((v.u >> 16) & 1u);  // RNE
    return (u16)(r >> 16);
}
__device__ __forceinline__ float b2f(u16 b) {
    union { unsigned u; float f; } v; v.u = ((unsigned)b) << 16; return v.f;
}
__device__ __forceinline__ float sigm(float x) {
    return __fdividef(1.f, 1.f + __expf(-x));
}
__device__ __forceinline__ float ftanh(float x) {
    float e = __expf(-2.f * fabsf(x));
    float r = __fdividef(1.f - e, 1.f + e);
    return copysignf(r, x);
}

template<int N> __device__ __forceinline__ void vmwait() {
    if constexpr (N == 0)        asm volatile("s_waitcnt vmcnt(0)" ::: "memory");
    else if constexpr (N == 2)   asm volatile("s_waitcnt vmcnt(2)" ::: "memory");
    else if constexpr (N == 3)   asm volatile("s_waitcnt vmcnt(3)" ::: "memory");
    else if constexpr (N == 4)   asm volatile("s_waitcnt vmcnt(4)" ::: "memory");
    else if constexpr (N == 6)   asm volatile("s_waitcnt vmcnt(6)" ::: "memory");
    else if constexpr (N == 8)   asm volatile("s_waitcnt vmcnt(8)" ::: "memory");
    else if constexpr (N == 16)  asm volatile("s_waitcnt vmcnt(16)" ::: "memory");
    else                         asm volatile("s_waitcnt vmcnt(0)" ::: "memory");
}

__device__ __forceinline__ void gload16(const u16* g, u16* l) {
    __builtin_amdgcn_global_load_lds(
        (const __attribute__((address_space(1))) void*)g,
        (__attribute__((address_space(3))) void*)l, 16, 0, 0);
}

// ---------------- vectorized fused epilogue (per-lane, NC contiguous cols) --
// EPI0 aux reads come from an LDS slice (child rows x WC cols, XOR-swizzled
// in 16B units). Bit-identical arithmetic to the scalar version.
template<int EPI, int NC, int WC>
__device__ __forceinline__ void epi_vec(
    const f32x4* va, int gr, int gc0,
    float* __restrict__ outf, u16* __restrict__ outb,
    u16* __restrict__ zrb, const u16* auxl, int lrow, int coffs, int outRow0)
{
    constexpr int NV = NC / 8;
    if constexpr (EPI == 1) {
        f32x4 ov[NC/4]; u16x8 hv[NV];
#pragma unroll
        for (int i = 0; i < NC; ++i) {
            float v = ftanh(va[i>>2][i&3]);
            ov[i>>2][i&3] = v; hv[i>>3][i&7] = f2b(v);
        }
        size_t o = (size_t)(outRow0 + gr) * H + gc0;
#pragma unroll
        for (int j = 0; j < NC/4; ++j) *(f32x4*)&outf[o + 4*j] = ov[j];
#pragma unroll
        for (int j = 0; j < NV; ++j) *(u16x8*)&outb[o + 8*j] = hv[j];
    } else if constexpr (EPI == 0) {
        auto aux_read = [&](int ch, int jj) -> u16x8 {
            int cr  = 4*lrow + ch;
            int key = (cr >> 2) & (WC/8 - 1);
            int j   = (coffs >> 3) + jj;
            return *(const u16x8*)&auxl[cr*WC + ((j ^ key) << 3)];
        };
        if (gc0 < H) {
            u16x8 zv[NV]; f32x4 hs[NC/4];
#pragma unroll
            for (int i = 0; i < NC; ++i) {
                zv[i>>3][i&7] = f2b(sigm(va[i>>2][i&3]));
                hs[i>>2][i&3] = 0.f;
            }
#pragma unroll
            for (int ch = 0; ch < 4; ++ch) {
#pragma unroll
                for (int j = 0; j < NV; ++j) {
                    u16x8 cv = aux_read(ch, j);
#pragma unroll
                    for (int k = 0; k < 8; ++k) {
                        int i = 8*j + k;
                        hs[i>>2][i&3] += b2f(cv[k]);
                    }
                }
            }
            u16x8 sv[NV];
#pragma unroll
            for (int i = 0; i < NC; ++i) sv[i>>3][i&7] = f2b(hs[i>>2][i&3]);
            size_t zo = (size_t)gr * 1024 + gc0;
#pragma unroll
            for (int j = 0; j < NV; ++j) *(u16x8*)&zrb[zo + 8*j] = zv[j];
#pragma unroll
            for (int j = 0; j < NV; ++j) *(u16x8*)&zrb[zo + H + 8*j] = sv[j];
        } else {
            f32x4 rr[NC/4];
#pragma unroll
            for (int i = 0; i < NC; ++i) rr[i>>2][i&3] = sigm(va[i>>2][i&3]);
            const int cc = gc0 - H;
#pragma unroll
            for (int ch = 0; ch < 4; ++ch) {
#pragma unroll
                for (int j = 0; j < NV; ++j) {
                    u16x8 cv = aux_read(ch, j);
                    u16x8 ov;
#pragma unroll
                    for (int k = 0; k < 8; ++k) {
                        int i = 8*j + k;
                        ov[k] = f2b(rr[i>>2][i&3] * b2f(cv[k]));
                    }
                    *(u16x8*)&outb[(size_t)gr*2048 + ch*H + cc + 8*j] = ov;
                }
            }
        }
    } else { // EPI == 2
        size_t zo = (size_t)gr * 1024 + gc0;
        u16x8 zv[NV], sv[NV];
#pragma unroll
        for (int j = 0; j < NV; ++j) zv[j] = *(const u16x8*)&zrb[zo + 8*j];
#pragma unroll
        for (int j = 0; j < NV; ++j) sv[j] = *(const u16x8*)&zrb[zo + H + 8*j];
        f32x4 ov[NC/4]; u16x8 hv[NV];
#pragma unroll
        for (int i = 0; i < NC; ++i) {
            float hc = ftanh(va[i>>2][i&3]);
            float z  = b2f(zv[i>>3][i&7]);
            float v  = b2f(sv[i>>3][i&7]) * z + (1.f - z) * hc;
            ov[i>>2][i&3] = v; hv[i>>3][i&7] = f2b(v);
        }
        size_t o = (size_t)(outRow0 + gr) * H + gc0;
#pragma unroll
        for (int j = 0; j < NC/4; ++j) *(f32x4*)&outf[o + 4*j] = ov[j];
#pragma unroll
        for (int j = 0; j < NV; ++j) *(u16x8*)&outb[o + 8*j] = hv[j];
    }
}

// ---- EPI0 aux slice staging: 64 child rows x WC cols into per-wave LDS ----
template<int WC>
__device__ __forceinline__ void stage_aux(
    u16* wls, const u16* auxg, int lane)
{
    constexpr int UPW = WC / 8;          // 16B units per row
    constexpr int NIT = 64 * UPW / 64;   // instructions per wave
#pragma unroll
    for (int it = 0; it < NIT; ++it) {
        int row = (it * 64 + lane) / UPW;
        int sp  = (lane & (UPW - 1)) ^ ((row >> 2) & (UPW - 1));
        gload16(auxg + row * H + sp * 8, &wls[it * 512]);
    }
}

// ---------------- fp32 -> bf16 conversion (all tensors, one launch) --------
__global__ void cvt_all(const float* __restrict__ s0, u16* __restrict__ d0, int n0,
                        const float* __restrict__ s1, u16* __restrict__ d1, int n1,
                        const float* __restrict__ s2, u16* __restrict__ d2, int n2,
                        const float* __restrict__ s3, u16* __restrict__ d3, int n3)
{
    int i = blockIdx.x * blockDim.x + threadIdx.x;
    int st = gridDim.x * blockDim.x;
    int tot = n0 + n1 + n2 + n3;
    for (; i < tot; i += st) {
        const float* s; u16* d; int k = i;
        if (k < n0)      { s = s0; d = d0; }
        else { k -= n0;
        if (k < n1)      { s = s1; d = d1; }
        else { k -= n1;
        if (k < n2)      { s = s2; d = d2; }
        else { k -= n2;    s = s3; d = d3; } } }
        float4 v = ((const float4*)s)[k];
        ushort4 o;
        o.x = f2b(v.x); o.y = f2b(v.y); o.z = f2b(v.z); o.w = f2b(v.w);
        ((ushort4*)d)[k] = o;
    }
}

// ====== 512-thread 256x256 kernel (leaf + L7-Uzr): wave tile 128x64 =========
// LDS-byte-per-MFMA geometry fix: 8 waves 2Mx4N, MI=8/NI=4 -> frag reads
// 96 KB + staging 32 KB per 256 MFMAs = 512 B/MFMA (vs 688 at 256x128).
// Schedule = audited R5 counted ring: NBUF=4 half-ring (K-half=32), depth-3
// prefetch, vmwait 8/4/0 (L=4 loads/thread/half), ONE barrier/half,
// stage(h+3) AFTER the barrier, setprio around MFMA, hoisted addressing.
// Single frag set (reg-dbuf proven neutral in R6) keeps regs ~210 < 256.
template<int EPI>
__global__ __launch_bounds__(512, 2) void gemm2c(
    const u16* __restrict__ A, int lda, int M, int K,
    const u16* __restrict__ Bm,
    const float* __restrict__ bias,
    float* __restrict__ outf,
    u16*  __restrict__ outb,
    u16*  __restrict__ zrb,
    const u16* __restrict__ auxb,
    int outRow0)
{
    constexpr int MI = 8, NI = 4;
    constexpr int AH = 256 * 32;          // u16 per A half-slot (16 KB)
    constexpr int BH = 256 * 32;          // u16 per B half-slot (16 KB)
    constexpr int L  = 4;                 // loads/thread/half (A:2 + B:2)

    __shared__ __align__(16) char smem[4 * (AH + BH) * 2];  // 128 KB
    u16* Asm = reinterpret_cast<u16*>(smem);
    u16* Bsm = reinterpret_cast<u16*>(smem) + 4 * AH;

    const int tid  = threadIdx.x;
    const int lane = tid & 63;
    const int wave = tid >> 6;
    const int wm = wave >> 2;             // 0..1 -> 128-row half of 256
    const int wn = wave & 3;              // 0..3 -> 64-col quarter of 256

    int bx, by;
    {
        const int gx = gridDim.x, gy = gridDim.y;
        int p = blockIdx.y * gx + blockIdx.x;
        if ((gy & 7) == 0) {
            int xcd = p & 7, slot = p >> 3;
            bx = slot % gx;
            by = (slot / gx) * 8 + xcd;
        } else { bx = blockIdx.x; by = blockIdx.y; }
    }
    const int row0 = by * 256;
    const int col0 = bx * 256;

    // ---- hoisted per-thread staging pointers (advance +32 per stage call) --
    const u16 *gA0, *gA1, *gB0, *gB1;
    int lA0, lA1, lB0, lB1;
    {
        int e8 = tid, row = e8 >> 2, jc = e8 & 3, js = jc ^ ((row >> 1) & 3);
        gA0 = A  + (size_t)(row0 + row) * lda + js * 8;  lA0 = e8 * 8;
        gB0 = Bm + (size_t)(col0 + row) * K   + js * 8;  lB0 = e8 * 8;
        int e9 = 512 + tid, row2 = e9 >> 2, jc2 = e9 & 3,
            js2 = jc2 ^ ((row2 >> 1) & 3);
        gA1 = A  + (size_t)(row0 + row2) * lda + js2 * 8; lA1 = e9 * 8;
        gB1 = Bm + (size_t)(col0 + row2) * K   + js2 * 8; lB1 = e9 * 8;
    }
    auto stage = [&](int slot) {
        gload16(gA0, &Asm[slot * AH + lA0]); gA0 += 32;
        gload16(gA1, &Asm[slot * AH + lA1]); gA1 += 32;
        gload16(gB0, &Bsm[slot * BH + lB0]); gB0 += 32;
        gload16(gB1, &Bsm[slot * BH + lB1]); gB1 += 32;
    };

    // ---- hoisted per-lane fragment offsets (u16 units) ----
    // Swizzle term (arow>>1)&3 is mi-independent (mi*16>>1 ≡ 0 mod 4).
    const int rl = lane & 15;
    const int qq = lane >> 4;
    const int ua   = qq ^ ((rl >> 1) & 3);
    const int aoff = (wm * 128 + rl) * 32 + ua * 8;
    const int boff = (wn * 64  + rl) * 32 + ua * 8;

    f32x4 acc[MI][NI] = {};
    const int nh = K / 32;                // 16 (leaf) or 64 (Uzr), >= 3

    stage(0); stage(1); stage(2);

    for (int h = 0; h < nh; ++h) {
        const int rem = nh - h;
        if (rem >= 3)      vmwait<2 * L>();   // drain h; leave h+1,h+2
        else if (rem == 2) vmwait<L>();
        else               vmwait<0>();
        __builtin_amdgcn_s_barrier();
        asm volatile("" ::: "memory");
        if (h + 3 < nh) stage((h + 3) & 3);

        const u16* aB = Asm + (h & 3) * AH + aoff;
        const u16* bB = Bsm + (h & 3) * BH + boff;
        bf16x8 fa[MI], fb[NI];
#pragma unroll
        for (int mi = 0; mi < MI; ++mi)
            fa[mi] = *(const bf16x8*)(aB + mi * 512);
#pragma unroll
        for (int ni = 0; ni < NI; ++ni)
            fb[ni] = *(const bf16x8*)(bB + ni * 512);
        __builtin_amdgcn_s_setprio(1);
#pragma unroll
        for (int mi = 0; mi < MI; ++mi)
#pragma unroll
            for (int ni = 0; ni < NI; ++ni)
                acc[mi][ni] = __builtin_amdgcn_mfma_f32_16x16x32_bf16(
                    fa[mi], fb[ni], acc[mi][ni], 0, 0, 0);
        __builtin_amdgcn_s_setprio(0);
    }

    // ---- epilogue: per-wave LDS transpose + (EPI0) coalesced aux restage ---
    float bcol[NI];
#pragma unroll
    for (int ni = 0; ni < NI; ++ni)
        bcol[ni] = bias[col0 + wn * 64 + ni * 16 + rl];

    __syncthreads();
    char* wreg = smem + wave * 8192;
    float* Csw = reinterpret_cast<float*>(wreg);
    u16*   wls = reinterpret_cast<u16*>(wreg);
    const int rq  = lane >> 4;
    const int rl2 = lane & 15;
#pragma unroll
    for (int mi = 0; mi < MI; ++mi) {
#pragma unroll
        for (int ni = 0; ni < NI; ++ni)
#pragma unroll
            for (int q = 0; q < 4; ++q)
                Csw[(rq*4 + q)*68 + ni*16 + rl2] = acc[mi][ni][q] + bcol[ni];
        asm volatile("s_waitcnt lgkmcnt(0)" ::: "memory");
        f32x4 va[4];
#pragma unroll
        for (int j = 0; j < 4; ++j)
            va[j] = *(const f32x4*)&Csw[rl2*68 + rq*16 + 4*j];
        if constexpr (EPI == 0) {
            asm volatile("s_waitcnt lgkmcnt(0)" ::: "memory");
            int c0 = ((col0 < H) ? col0 : col0 - H) + wn * 64;
            const u16* auxg = auxb + (size_t)(4*(row0 + wm*128 + mi*16)) * H + c0;
            stage_aux<64>(wls, auxg, lane);
            vmwait<0>();
        }
        int gr  = row0 + wm*128 + mi*16 + rl2;
        int gc0 = col0 + wn*64 + rq*16;
        if (gr < M)
            epi_vec<EPI, 16, 64>(va, gr, gc0, outf, outb, zrb, wls, rl2, rq*16, outRow0);
    }
}

// ====== 512-thread 256x128 deep-pipeline kernel (L7-Uh): R9-best config =====
// NBUF=4 half-ring, depth-3 prefetch, counted vmcnt, ONE barrier/half,
// reg-dbuf frags, setprio, hoisted addressing.
template<int EPI>
__global__ __launch_bounds__(512, 2) void gemm8p(
    const u16* __restrict__ A, int lda, int M, int K,
    const u16* __restrict__ Bm,
    const float* __restrict__ bias,
    float* __restrict__ outf,
    u16*  __restrict__ outb,
    u16*  __restrict__ zrb,
    const u16* __restrict__ auxb,
    int outRow0)
{
    constexpr int MI = 4, NI = 4;
    constexpr int AH = 256 * 32;          // u16 per A half-slot (16 KB)
    constexpr int BH = 128 * 32;          // u16 per B half-slot (8 KB)
    constexpr int L  = 3;                 // loads/thread/half

    __shared__ __align__(16) char smem[(4 * AH + 4 * BH) * 2];  // 96 KB
    u16* Asm = reinterpret_cast<u16*>(smem);
    u16* Bsm = reinterpret_cast<u16*>(smem) + 4 * AH;

    const int tid  = threadIdx.x;
    const int lane = tid & 63;
    const int wave = tid >> 6;
    const int wm = wave >> 1;             // 0..3 -> 64-row band of 256
    const int wn = wave & 1;              // 0..1 -> 64-col half of 128

    int bx, by;
    {
        const int gx = gridDim.x, gy = gridDim.y;
        int p = blockIdx.y * gx + blockIdx.x;
        if ((gy & 7) == 0) {
            int xcd = p & 7, slot = p >> 3;
            bx = slot % gx;
            by = (slot / gx) * 8 + xcd;
        } else { bx = blockIdx.x; by = blockIdx.y; }
    }
    const int row0 = by * 256;
    const int col0 = bx * 128;

    const u16 *gA0, *gA1, *gB;
    int ldsA0, ldsA1, ldsB;
    {
        int e8 = tid, row = e8 >> 2, jc = e8 & 3, js = jc ^ ((row >> 1) & 3);
        gA0 = A + (size_t)(row0 + row) * lda + js * 8;  ldsA0 = e8 * 8;
        int e9 = 512 + tid, row2 = e9 >> 2, jc2 = e9 & 3,
            js2 = jc2 ^ ((row2 >> 1) & 3);
        gA1 = A + (size_t)(row0 + row2) * lda + js2 * 8; ldsA1 = e9 * 8;
        int br = tid >> 2, bjc = tid & 3, bjs = bjc ^ ((br >> 1) & 3);
        gB = Bm + (size_t)(col0 + br) * K + bjs * 8;     ldsB = tid * 8;
    }
    auto stage = [&](int slot) {
        gload16(gA0, &Asm[slot * AH + ldsA0]); gA0 += 32;
        gload16(gA1, &Asm[slot * AH + ldsA1]); gA1 += 32;
        gload16(gB,  &Bsm[slot * BH + ldsB]);  gB  += 32;
    };

    const int rl = lane & 15;
    const int qq = lane >> 4;
    const int ua   = qq ^ ((rl >> 1) & 3);
    const int aoff = (wm * 64 + rl) * 32 + ua * 8;
    const int boff = (wn * 64 + rl) * 32 + ua * 8;

    auto ld_frags = [&](int h, bf16x8 (&fa)[MI], bf16x8 (&fb)[NI]) {
        const u16* aB = Asm + (h & 3) * AH + aoff;
        const u16* bB = Bsm + (h & 3) * BH + boff;
#pragma unroll
        for (int mi = 0; mi < MI; ++mi)
            fa[mi] = *(const bf16x8*)(aB + mi * 512);
#pragma unroll
        for (int ni = 0; ni < NI; ++ni)
            fb[ni] = *(const bf16x8*)(bB + ni * 512);
    };

    f32x4 acc[MI][NI] = {};
    const int nh = K / 32;
    bf16x8 fa0[MI], fb0[NI], fa1[MI], fb1[NI];

    stage(0); stage(1); stage(2);
    vmwait<2 * L>();
    __builtin_amdgcn_s_barrier();
    asm volatile("" ::: "memory");
    ld_frags(0, fa0, fb0);

    auto iter = [&](int h, bf16x8 (&cfa)[MI], bf16x8 (&cfb)[NI],
                           bf16x8 (&nfa)[MI], bf16x8 (&nfb)[NI]) {
        if (h + 2 < nh) vmwait<L>();
        else            vmwait<0>();
        __builtin_amdgcn_s_barrier();
        asm volatile("" ::: "memory");
        if (h + 3 < nh) stage((h + 3) & 3);
        if (h + 1 < nh) ld_frags(h + 1, nfa, nfb);
        __builtin_amdgcn_s_setprio(1);
#pragma unroll
        for (int mi = 0; mi < MI; ++mi)
#pragma unroll
            for (int ni = 0; ni < NI; ++ni)
                acc[mi][ni] = __builtin_amdgcn_mfma_f32_16x16x32_bf16(
                    cfa[mi], cfb[ni], acc[mi][ni], 0, 0, 0);
        __builtin_amdgcn_s_setprio(0);
    };

    for (int h = 0; h < nh; h += 2) {
        iter(h,     fa0, fb0, fa1, fb1);
        iter(h + 1, fa1, fb1, fa0, fb0);
    }

    // ---- epilogue ----
    float bcol[NI];
#pragma unroll
    for (int ni = 0; ni < NI; ++ni)
        bcol[ni] = bias[col0 + wn * 64 + ni * 16 + rl];

    __syncthreads();
    char* wreg = smem + wave * 8192;
    float* Csw = reinterpret_cast<float*>(wreg);
    u16*   wls = reinterpret_cast<u16*>(wreg);
    const int rq  = lane >> 4;
    const int rl2 = lane & 15;
#pragma unroll
    for (int mi = 0; mi < MI; ++mi) {
#pragma unroll
        for (int ni = 0; ni < NI; ++ni)
#pragma unroll
            for (int q = 0; q < 4; ++q)
                Csw[(rq*4 + q)*68 + ni*16 + rl2] = acc[mi][ni][q] + bcol[ni];
        asm volatile("s_waitcnt lgkmcnt(0)" ::: "memory");
        f32x4 va[4];
#pragma unroll
        for (int j = 0; j < 4; ++j)
            va[j] = *(const f32x4*)&Csw[rl2*68 + rq*16 + 4*j];
        if constexpr (EPI == 0) {
            asm volatile("s_waitcnt lgkmcnt(0)" ::: "memory");
            int c0 = ((col0 < H) ? col0 : col0 - H) + wn * 64;
            const u16* auxg = auxb + (size_t)(4*(row0 + wm*64 + mi*16)) * H + c0;
            stage_aux<64>(wls, auxg, lane);
            vmwait<0>();
        }
        int gr  = row0 + wm*64 + mi*16 + rl2;
        int gc0 = col0 + wn*64 + rq*16;
        if (gr < M)
            epi_vec<EPI, 16, 64>(va, gr, gc0, outf, outb, zrb, wls, rl2, rq*16, outRow0);
    }
}

// ============ 512-thread 128x128 kernel (L6): 8 waves, BK=32 ================
template<int EPI>
__global__ __launch_bounds__(512) void gemm512(
    const u16* __restrict__ A, int lda, int M, int K,
    const u16* __restrict__ Bm,
    const float* __restrict__ bias,
    float* __restrict__ outf,
    u16*  __restrict__ outb,
    u16*  __restrict__ zrb,
    const u16* __restrict__ auxb,
    int outRow0)
{
    __shared__ __align__(16) char smem[4*128*32*2 * 2];  // 65536 B
    u16* Asm = reinterpret_cast<u16*>(smem);
    u16* Bsm = reinterpret_cast<u16*>(smem) + 4 * 128 * 32;

    const int tid  = threadIdx.x;
    const int lane = tid & 63;
    const int wave = tid >> 6;
    const int wm = wave >> 2;
    const int wn = wave & 3;

    int bx, by;
    {
        const int gx = gridDim.x, gy = gridDim.y;
        int p = blockIdx.y * gx + blockIdx.x;
        if ((gy & 7) == 0) {
            int xcd = p & 7, slot = p >> 3;
            bx = slot % gx;
            by = (slot / gx) * 8 + xcd;
        } else { bx = blockIdx.x; by = blockIdx.y; }
    }
    const int row0 = by * 128;
    const int col0 = bx * 128;

    const u16 *gA, *gB;
    int ldsE;
    {
        int row = tid >> 2, jc = tid & 3, js = jc ^ ((row >> 1) & 3);
        gA = A  + (size_t)(row0 + row) * lda + js * 8;
        gB = Bm + (size_t)(col0 + row) * K   + js * 8;
        ldsE = tid * 8;
    }
    auto stage = [&](int b) {
        gload16(gA, &Asm[b * (128*32) + ldsE]); gA += 32;
        gload16(gB, &Bsm[b * (128*32) + ldsE]); gB += 32;
    };

    const int rl = lane & 15;
    const int qq = lane >> 4;
    const int ua   = qq ^ ((rl >> 1) & 3);
    const int aoff = (wm * 64 + rl) * 32 + ua * 8;
    const int boff = (wn * 32 + rl) * 32 + ua * 8;

    f32x4 acc[4][2] = {};
    const int nt = K / 32;
    stage(0);
    stage(1);

    for (int t = 0; t < nt; ++t) {
        if (t + 2 < nt) {
            stage((t + 2) & 3);
            vmwait<4>();
        } else if (t + 2 == nt) {
            vmwait<2>();
        } else {
            vmwait<0>();
        }
        __builtin_amdgcn_s_barrier();
        asm volatile("" ::: "memory");

        const u16* aB = Asm + (t & 3) * (128*32) + aoff;
        const u16* bB = Bsm + (t & 3) * (128*32) + boff;
        bf16x8 af[4], bfr[2];
#pragma unroll
        for (int mi = 0; mi < 4; ++mi)
            af[mi] = *(const bf16x8*)(aB + mi * 512);
#pragma unroll
        for (int ni = 0; ni < 2; ++ni)
            bfr[ni] = *(const bf16x8*)(bB + ni * 512);
#pragma unroll
        for (int mi = 0; mi < 4; ++mi)
#pragma unroll
            for (int ni = 0; ni < 2; ++ni)
                acc[mi][ni] = __builtin_amdgcn_mfma_f32_16x16x32_bf16(
                    af[mi], bfr[ni], acc[mi][ni], 0, 0, 0);
    }

    // ---- epilogue ----
    float bcol[2];
#pragma unroll
    for (int ni = 0; ni < 2; ++ni)
        bcol[ni] = bias[col0 + wn * 32 + ni * 16 + rl];

    __syncthreads();
    char* wreg = smem + wave * 8192;
    float* Csw = reinterpret_cast<float*>(wreg);
    u16*   wls = reinterpret_cast<u16*>(wreg);
    const int rq  = lane >> 4;
    const int rl2 = lane & 15;
#pragma unroll
    for (int mi = 0; mi < 4; ++mi) {
#pragma unroll
        for (int ni = 0; ni < 2; ++ni)
#pragma unroll
            for (int q = 0; q < 4; ++q)
                Csw[(rq*4 + q)*36 + ni*16 + rl2] = acc[mi][ni][q] + bcol[ni];
        asm volatile("s_waitcnt lgkmcnt(0)" ::: "memory");
        f32x4 va[2];
#pragma unroll
        for (int j = 0; j < 2; ++j)
            va[j] = *(const f32x4*)&Csw[rl2*36 + rq*8 + 4*j];
        if constexpr (EPI == 0) {
            asm volatile("s_waitcnt lgkmcnt(0)" ::: "memory");
            int c0 = ((col0 < H) ? col0 : col0 - H) + wn * 32;
            const u16* auxg = auxb + (size_t)(4*(row0 + wm*64 + mi*16)) * H + c0;
            stage_aux<32>(wls, auxg, lane);
            vmwait<0>();
        }
        int gr  = row0 + wm*64 + mi*16 + rl2;
        int gc0 = col0 + wn*32 + rq*8;
        if (gr < M)
            epi_vec<EPI, 8, 32>(va, gr, gc0, outf, outb, zrb, wls, rl2, rq*8, outRow0);
    }
}

// ====== 256-thread 64x64 split-K kernel (small levels, m <= 1024) ===========
// 4 waves each own K/4; wave-PRIVATE LDS ring (NBUF=3, BK=32, depth-2
// prefetch, counted per-wave vmcnt 16/8/0, NO barriers in the K-loop).
// Then deterministic 4-partial LDS reduction (w0+w1+w2+w3) + fused epilogue.
template<int EPI>
__global__ __launch_bounds__(256, 1) void gemm_sk(
    const u16* __restrict__ A, int lda, int M, int K,
    const u16* __restrict__ Bm,
    const float* __restrict__ bias,
    float* __restrict__ outf,
    u16*  __restrict__ outb,
    u16*  __restrict__ zrb,
    const u16* __restrict__ auxb,
    int outRow0)
{
    __shared__ __align__(16) char smem[98304];   // 96 KB
    u16* ring = reinterpret_cast<u16*>(smem);    // 4 waves x 3 slots x 8 KB

    const int tid  = threadIdx.x;
    const int lane = tid & 63;
    const int wave = tid >> 6;                   // 0..3 -> K chunk
    const int row0 = blockIdx.y * 64;
    const int col0 = blockIdx.x * 64;
    const int KC   = K >> 2;                     // 512
    const int kb0  = wave * KC;
    const int NS   = KC / 32;                    // 16

    u16* wring = ring + wave * 12288;            // u16 units (24 KB)

    auto stage = [&](int sl, int kt) {
        u16* As = wring + sl * 4096;
        u16* Bs = As + 2048;
#pragma unroll
        for (int it = 0; it < 4; ++it) {
            int e8  = it * 64 + lane;
            int row = e8 >> 2;                   // 0..63
            int jc  = e8 & 3;
            int js  = jc ^ ((row >> 1) & 3);
            int ar = row0 + row; if (ar >= M) ar = M - 1;
            gload16(A + (size_t)ar * lda + kt + js * 8, &As[e8 * 8]);
            gload16(Bm + (size_t)(col0 + row) * K + kt + js * 8, &Bs[e8 * 8]);
        }
    };

    const int rl = lane & 15;
    const int qq = lane >> 4;
    const int ua   = qq ^ ((rl >> 1) & 3);
    const int aoff = rl * 32 + ua * 8;

    f32x4 acc[4][4] = {};
    stage(0, kb0);
    stage(1, kb0 + 32);

    for (int s = 0; s < NS; ++s) {
        if (s + 2 < NS) { stage((s + 2) % 3, kb0 + (s + 2) * 32); vmwait<16>(); }
        else if (s + 1 < NS) vmwait<8>();
        else                 vmwait<0>();
        asm volatile("" ::: "memory");
        const u16* As = wring + (s % 3) * 4096;
        const u16* Bs = As + 2048;
        bf16x8 af[4], bfr[4];
#pragma unroll
        for (int mi = 0; mi < 4; ++mi)
            af[mi] = *(const bf16x8*)&As[aoff + mi * 512];
#pragma unroll
        for (int ni = 0; ni < 4; ++ni)
            bfr[ni] = *(const bf16x8*)&Bs[aoff + ni * 512];
#pragma unroll
        for (int mi = 0; mi < 4; ++mi)
#pragma unroll
            for (int ni = 0; ni < 4; ++ni)
                acc[mi][ni] = __builtin_amdgcn_mfma_f32_16x16x32_bf16(
                    af[mi], bfr[ni], acc[mi][ni], 0, 0, 0);
    }

    // ---- partials to LDS (deterministic reduce order w0..w3) ----
    __syncthreads();                             // all waves done with rings
    float* P  = reinterpret_cast<float*>(smem);  // 4 x 4096 f32 = 64 KB
    float* Pw = P + wave * 4096;
    const int rq = lane >> 4;
#pragma unroll
    for (int mi = 0; mi < 4; ++mi)
#pragma unroll
        for (int ni = 0; ni < 4; ++ni)
#pragma unroll
            for (int q = 0; q < 4; ++q)
                Pw[(mi*16 + rq*4 + q) * 64 + ni*16 + rl] = acc[mi][ni][q];
    asm volatile("s_waitcnt lgkmcnt(0)" ::: "memory");
    __syncthreads();

    // ---- (EPI0) stage aux slice: 256 child rows x 64 cols, swizzled ----
    u16* auxl = reinterpret_cast<u16*>(smem + 65536);   // 32 KB
    if constexpr (EPI == 0) {
        int c0 = (col0 < H) ? col0 : col0 - H;
        const u16* auxg = auxb + (size_t)(4 * row0) * H + c0;
        const int maxr = 4 * (M - row0);                 // valid child rows
#pragma unroll
        for (int it = 0; it < 8; ++it) {
            int e   = it * 256 + tid;
            int row = e >> 3;                            // 0..255
            int crow = row; if (crow >= maxr) crow = maxr - 1;
            int sp  = (e & 7) ^ ((row >> 2) & 7);
            gload16(auxg + (size_t)crow * H + sp * 8, &auxl[e * 8]);
        }
    }

    // ---- reduce + bias + epilogue (thread -> 1 row x 16 cols) ----
    const int orow = tid >> 2;                   // 0..63
    const int cq   = tid & 3;
    f32x4 va[4];
#pragma unroll
    for (int j = 0; j < 4; ++j) {
        f32x4 v = *(const f32x4*)&P[orow*64 + cq*16 + 4*j];
#pragma unroll
        for (int w = 1; w < 4; ++w)
            v += *(const f32x4*)&P[w*4096 + orow*64 + cq*16 + 4*j];
        v += *(const f32x4*)&bias[col0 + cq*16 + 4*j];
        va[j] = v;
    }
    if constexpr (EPI == 0) vmwait<0>();
    asm volatile("s_waitcnt lgkmcnt(0)" ::: "memory");
    int gr = row0 + orow;
    if (gr < M)
        epi_vec<EPI, 16, 64>(va, gr, col0 + cq*16, outf, outb, zrb,
                             auxl, orow, cq*16, outRow0);
}

extern "C" void kernel_launch(void* const* d_in, const int* in_sizes, int n_in,
                              void* d_out, int out_size, void* d_ws, size_t ws_size,
                              hipStream_t stream) {
    const float* x     = (const float*)d_in[0];
    const float* Ww    = (const float*)d_in[1];
    const float* Wb    = (const float*)d_in[2];
    const float* Uzr_w = (const float*)d_in[3];
    const float* Uzr_b = (const float*)d_in[4];
    const float* Uh_w  = (const float*)d_in[5];
    const float* Uh_b  = (const float*)d_in[6];
    float* out = (float*)d_out;

    char* ws = (char*)d_ws;
    size_t off = 0;
    u16* hb   = (u16*)(ws + off); off += (size_t)NNODES * H * 2;       // 89.5 MB
    u16* zr   = (u16*)(ws + off); off += (size_t)16384 * 1024 * 2;     // 32 MB
    u16* rhxb = (u16*)(ws + off); off += (size_t)16384 * 2048 * 2;     // 64 MB
    u16* Wwb  = (u16*)(ws + off); off += (size_t)512 * 512 * 2;
    u16* Uzrb = (u16*)(ws + off); off += (size_t)1024 * 2048 * 2;
    u16* Uhb  = (u16*)(ws + off); off += (size_t)512 * 2048 * 2;

    // 1) convert weights + leaf x to bf16 (single launch)
    cvt_all<<<dim3(8192), 256, 0, stream>>>(
        Ww, Wwb, 512 * 512 / 4,
        Uzr_w, Uzrb, 1024 * 2048 / 4,
        Uh_w, Uhb, 512 * 2048 / 4,
        x + (size_t)LEAF0 * H, rhxb, NLEAF * H / 4);

    // 2) leaf GEMM: h = tanh(x @ Ww^T + Wb) — 256x256 low-LDS-per-MFMA
    gemm2c<1><<<dim3(H / 256, NLEAF / 256), 512, 0, stream>>>(
        rhxb, H, NLEAF, H, Wwb, Wb, out, hb, nullptr, nullptr, LEAF0);

    // 3) levels 7..0
    static const int pow4[9] = {1, 4, 16, 64, 256, 1024, 4096, 16384, 65536};
    int starts[10]; starts[0] = 0;
    for (int l = 0; l < 9; ++l) starts[l + 1] = starts[l] + pow4[l];

    for (int l = 7; l >= 0; --l) {
        int s = starts[l], m = pow4[l];
        int cs = 4 * s + 1;  // children rows are contiguous: [cs, cs+4m)
        if (m >= 16384) {
            // Uzr: 256x256 (grid 4x64 = 256 blocks = 1/CU exactly)
            gemm2c<0><<<dim3(1024 / 256, m / 256), 512, 0, stream>>>(
                hb + (size_t)cs * H, 2048, m, 2048, Uzrb, Uzr_b,
                nullptr, rhxb, zr, hb + (size_t)cs * H, 0);
            // Uh: 256x128 (N=512 -> 256x256 would leave half the GPU idle)
            gemm8p<2><<<dim3(H / 128, m / 256), 512, 0, stream>>>(
                rhxb, 2048, m, 2048, Uhb, Uh_b,
                out, hb, zr, nullptr, s);
        } else if (m >= 4096) {
            int gm = (m + 127) / 128;
            gemm512<0><<<dim3(1024 / 128, gm), 512, 0, stream>>>(
                hb + (size_t)cs * H, 2048, m, 2048, Uzrb, Uzr_b,
                nullptr, rhxb, zr, hb + (size_t)cs * H, 0);
            gemm512<2><<<dim3(H / 128, gm), 512, 0, stream>>>(
                rhxb, 2048, m, 2048, Uhb, Uh_b,
                out, hb, zr, nullptr, s);
        } else {
            // small levels: 64x64 split-K kernel, grid fills the GPU better
            int gm = (m + 63) / 64;
            gemm_sk<0><<<dim3(1024 / 64, gm), 256, 0, stream>>>(
                hb + (size_t)cs * H, 2048, m, 2048, Uzrb, Uzr_b,
                nullptr, rhxb, zr, hb + (size_t)cs * H, 0);
            gemm_sk<2><<<dim3(512 / 64, gm), 256, 0, stream>>>(
                rhxb, 2048, m, 2048, Uhb, Uh_b,
                out, hb, zr, nullptr, s);
        }
    }
}